// Round 2
// baseline (106.322 us; speedup 1.0000x reference)
//
#include <hip/hip_runtime.h>
#include <math.h>

#define IN_DIM 768
#define OUT_DIM 768
#define BATCH 32

#define O_TILE 16                     // outputs per block
#define I_SPLIT 24                    // blocks along i
#define I_CHUNK (IN_DIM / I_SPLIT)    // 32 inputs per block
// thread map: 256 = 32 batch-lanes x 8 i-groups; each i-group owns 4 contiguous i

// Kernel 1 (tiny): seed y[b][o] = bias_w[o]
__global__ __launch_bounds__(256) void seed_y(const float* __restrict__ bias_w,
                                              float* __restrict__ y) {
    int idx = blockIdx.x * 256 + threadIdx.x;
    if (idx < BATCH * OUT_DIM) y[idx] = bias_w[idx % OUT_DIM];
}

// Kernel 2: fused sin-basis + reduce. y[b,o] += sum_i ssp*dot8(coef,sin) + sb*silu
__global__ __launch_bounds__(256, 4) void slayer_fused(const float* __restrict__ x,
                                                       const float* __restrict__ grid,
                                                       const float* __restrict__ coef,
                                                       const float* __restrict__ scale_base,
                                                       const float* __restrict__ scale_sp,
                                                       float* __restrict__ y) {
    __shared__ float red[8 * 512];                 // [g][b*O_TILE+ol], 16 KB
    const int t  = threadIdx.x;
    const int b  = t & 31;                         // batch lane
    const int g  = t >> 5;                         // i-group 0..7
    const int ob = blockIdx.x / I_SPLIT;
    const int is = blockIdx.x % I_SPLIT;
    const int o0 = ob * O_TILE;
    const int i0 = is * I_CHUNK + g * 4;           // this thread's 4 contiguous i

    // grid (wave-uniform, 8 floats) -> registers
    float gr[8];
#pragma unroll
    for (int j = 0; j < 8; ++j) gr[j] = grid[j];

    // x for the 4 owned i's (16B aligned: i0 is a multiple of 4)
    const float4 xv = *(const float4*)(x + b * IN_DIM + i0);
    const float xq[4] = {xv.x, xv.y, xv.z, xv.w};

    // sin table + silu, held in registers across the whole ol loop
    float sn[4][8];
    float si[4];
#pragma unroll
    for (int q = 0; q < 4; ++q) {
#pragma unroll
        for (int j = 0; j < 8; ++j) sn[q][j] = __sinf(gr[j] * xq[q]);
        si[q] = xq[q] / (1.0f + __expf(-xq[q]));
    }

    // base pointers for this thread's (o0, i0) stripe
    const float* cbase = coef + ((size_t)(o0 * IN_DIM + i0)) * 8;   // 4 rows = 128B contiguous
    const float* spb   = scale_sp + o0 * IN_DIM + i0;
    const float* sbb   = scale_base + o0 * IN_DIM + i0;

    float acc[O_TILE];
#pragma unroll
    for (int ol = 0; ol < O_TILE; ++ol) acc[ol] = 0.0f;

#pragma unroll
    for (int ol = 0; ol < O_TILE; ++ol) {
        const float* c = cbase + (size_t)ol * (IN_DIM * 8);         // ol*24576B stride
        const float4 sp4 = *(const float4*)(spb + ol * IN_DIM);
        const float4 sb4 = *(const float4*)(sbb + ol * IN_DIM);
        const float spq[4] = {sp4.x, sp4.y, sp4.z, sp4.w};
        const float sbq[4] = {sb4.x, sb4.y, sb4.z, sb4.w};
#pragma unroll
        for (int q = 0; q < 4; ++q) {
            const float4 c0 = *(const float4*)(c + q * 8);
            const float4 c1 = *(const float4*)(c + q * 8 + 4);
            float dot = c0.x * sn[q][0] + c0.y * sn[q][1]
                      + c0.z * sn[q][2] + c0.w * sn[q][3]
                      + c1.x * sn[q][4] + c1.y * sn[q][5]
                      + c1.z * sn[q][6] + c1.w * sn[q][7];
            acc[ol] += spq[q] * dot + sbq[q] * si[q];
        }
    }

    // block reduction over the 8 i-groups
#pragma unroll
    for (int ol = 0; ol < O_TILE; ++ol)
        red[g * 512 + b * O_TILE + ol] = acc[ol];
    __syncthreads();

#pragma unroll
    for (int rep = 0; rep < 2; ++rep) {
        const int idx2 = t + rep * 256;            // 0..511 covers 32b x 16ol
        const int b2  = idx2 >> 4;
        const int ol2 = idx2 & 15;
        float sum = 0.0f;
#pragma unroll
        for (int g2 = 0; g2 < 8; ++g2) sum += red[g2 * 512 + idx2];
        atomicAdd(&y[b2 * OUT_DIM + o0 + ol2], sum);
    }
}

extern "C" void kernel_launch(void* const* d_in, const int* in_sizes, int n_in,
                              void* d_out, int out_size, void* d_ws, size_t ws_size,
                              hipStream_t stream) {
    const float* x          = (const float*)d_in[0];  // 32*768
    const float* grid       = (const float*)d_in[1];  // 8
    const float* coef       = (const float*)d_in[2];  // 589824*8
    const float* bias_w     = (const float*)d_in[3];  // 768
    const float* scale_base = (const float*)d_in[4];  // 589824
    const float* scale_sp   = (const float*)d_in[5];  // 589824
    float* y = (float*)d_out;                          // 32*768

    seed_y<<<(BATCH * OUT_DIM + 255) / 256, 256, 0, stream>>>(bias_w, y);
    slayer_fused<<<(OUT_DIM / O_TILE) * I_SPLIT, 256, 0, stream>>>(x, grid, coef,
                                                                   scale_base, scale_sp, y);
}

// Round 3
// 105.263 us; speedup vs baseline: 1.0101x; 1.0101x over previous
//
#include <hip/hip_runtime.h>
#include <math.h>

#define IN_DIM 768
#define OUT_DIM 768
#define BATCH 32

#define O_TILE 16                     // outputs per block
#define I_SPLIT 24                    // blocks along i
#define I_CHUNK (IN_DIM / I_SPLIT)    // 32 inputs per block
// thread map: 256 = 32 batch-lanes x 8 i-groups; each i-group owns 4 contiguous i

// Fused sin-basis + reduce. y[b,o] += sum_i ssp*dot8(coef,sin) + sb*silu (+ bias once)
__global__ __launch_bounds__(256, 4) void slayer_fused(const float* __restrict__ x,
                                                       const float* __restrict__ grid,
                                                       const float* __restrict__ coef,
                                                       const float* __restrict__ scale_base,
                                                       const float* __restrict__ scale_sp,
                                                       const float* __restrict__ bias_w,
                                                       float* __restrict__ y) {
    __shared__ float red[8 * 512];                 // [g][b*O_TILE+ol], 16 KB
    const int t  = threadIdx.x;
    const int b  = t & 31;                         // batch lane
    const int g  = t >> 5;                         // i-group 0..7
    const int ob = blockIdx.x / I_SPLIT;
    const int is = blockIdx.x % I_SPLIT;
    const int o0 = ob * O_TILE;
    const int i0 = is * I_CHUNK + g * 4;           // this thread's 4 contiguous i

    // grid (wave-uniform, 8 floats) -> registers
    float gr[8];
#pragma unroll
    for (int j = 0; j < 8; ++j) gr[j] = grid[j];

    // x for the 4 owned i's (16B aligned: i0 is a multiple of 4)
    const float4 xv = *(const float4*)(x + b * IN_DIM + i0);
    const float xq[4] = {xv.x, xv.y, xv.z, xv.w};

    // sin table + silu, held in registers across the whole ol loop
    float sn[4][8];
    float si[4];
#pragma unroll
    for (int q = 0; q < 4; ++q) {
#pragma unroll
        for (int j = 0; j < 8; ++j) sn[q][j] = __sinf(gr[j] * xq[q]);
        si[q] = xq[q] / (1.0f + __expf(-xq[q]));
    }

    // base pointers for this thread's (o0, i0) stripe
    const float* cbase = coef + ((size_t)(o0 * IN_DIM + i0)) * 8;   // 4 rows = 128B contiguous
    const float* spb   = scale_sp + o0 * IN_DIM + i0;
    const float* sbb   = scale_base + o0 * IN_DIM + i0;

    float acc[O_TILE];
#pragma unroll
    for (int ol = 0; ol < O_TILE; ++ol) acc[ol] = 0.0f;

#pragma unroll
    for (int ol = 0; ol < O_TILE; ++ol) {
        const float* c = cbase + (size_t)ol * (IN_DIM * 8);         // ol*24576B stride
        const float4 sp4 = *(const float4*)(spb + ol * IN_DIM);
        const float4 sb4 = *(const float4*)(sbb + ol * IN_DIM);
        const float spq[4] = {sp4.x, sp4.y, sp4.z, sp4.w};
        const float sbq[4] = {sb4.x, sb4.y, sb4.z, sb4.w};
#pragma unroll
        for (int q = 0; q < 4; ++q) {
            const float4 c0 = *(const float4*)(c + q * 8);
            const float4 c1 = *(const float4*)(c + q * 8 + 4);
            float dot = c0.x * sn[q][0] + c0.y * sn[q][1]
                      + c0.z * sn[q][2] + c0.w * sn[q][3]
                      + c1.x * sn[q][4] + c1.y * sn[q][5]
                      + c1.z * sn[q][6] + c1.w * sn[q][7];
            acc[ol] += spq[q] * dot + sbq[q] * si[q];
        }
    }

    // block reduction over the 8 i-groups
#pragma unroll
    for (int ol = 0; ol < O_TILE; ++ol)
        red[g * 512 + b * O_TILE + ol] = acc[ol];
    __syncthreads();

#pragma unroll
    for (int rep = 0; rep < 2; ++rep) {
        const int idx2 = t + rep * 256;            // 0..511 covers 32b x 16ol
        const int b2  = idx2 >> 4;
        const int ol2 = idx2 & 15;
        float sum = 0.0f;
#pragma unroll
        for (int g2 = 0; g2 < 8; ++g2) sum += red[g2 * 512 + idx2];
        if (is == 0) sum += bias_w[o0 + ol2];      // bias added exactly once per (b,o)
        atomicAdd(&y[b2 * OUT_DIM + o0 + ol2], sum);
    }
}

extern "C" void kernel_launch(void* const* d_in, const int* in_sizes, int n_in,
                              void* d_out, int out_size, void* d_ws, size_t ws_size,
                              hipStream_t stream) {
    const float* x          = (const float*)d_in[0];  // 32*768
    const float* grid       = (const float*)d_in[1];  // 8
    const float* coef       = (const float*)d_in[2];  // 589824*8
    const float* bias_w     = (const float*)d_in[3];  // 768
    const float* scale_base = (const float*)d_in[4];  // 589824
    const float* scale_sp   = (const float*)d_in[5];  // 589824
    float* y = (float*)d_out;                          // 32*768

    // zero-init output (graph-capturable memset node); bias folded into kernel
    hipMemsetAsync(d_out, 0, (size_t)out_size * sizeof(float), stream);
    slayer_fused<<<(OUT_DIM / O_TILE) * I_SPLIT, 256, 0, stream>>>(x, grid, coef,
                                                                   scale_base, scale_sp,
                                                                   bias_w, y);
}